// Round 1
// baseline (24.214 us; speedup 1.0000x reference)
//
#include <hip/hip_runtime.h>

#define KDIM 1024
#define DDIM 128
#define TS   32
#define LDP  132   // padded LDS row stride (floats): breaks stride-512B bank aliasing

// ---------------------------------------------------------------------------
// Kernel 1: U = span @ (W1a + W1c) + b1 ; V = ant @ (W1b - W1c)
// grid = 128 blocks (64 row-blocks x 2 matrices), 256 threads.
// Each block: 16 rows of one matrix. W1 slices combined on the fly (L2-hot).
// ---------------------------------------------------------------------------
__global__ __launch_bounds__(256) void prep_uv(
    const float* __restrict__ span, const float* __restrict__ ant,
    const float* __restrict__ W1,   const float* __restrict__ b1,
    float* __restrict__ U, float* __restrict__ V)
{
    __shared__ float a_lds[16 * DDIM];   // 8 KB

    const int mat  = blockIdx.x & 1;     // 0 -> U (span), 1 -> V (ant)
    const int rblk = blockIdx.x >> 1;    // 0..63, 16 rows each
    const float* __restrict__ A = mat ? ant : span;
    float* __restrict__ outp    = mat ? V : U;
    const int tid = threadIdx.x;

    // stage 16 input rows (2048 floats) -> 2 float4 per thread
    {
        const float4* src = (const float4*)(A + rblk * 16 * DDIM);
        float4* dst = (float4*)a_lds;
        dst[tid]       = src[tid];
        dst[tid + 256] = src[tid + 256];
    }
    __syncthreads();

    const int c  = tid & 127;    // output column
    const int rg = tid >> 7;     // 0/1 -> rows rg*8 .. rg*8+7
    float acc[8];
    const float binit = mat ? 0.0f : b1[c];
#pragma unroll
    for (int r = 0; r < 8; ++r) acc[r] = binit;

    const float* __restrict__ Wx = W1 + (mat ? DDIM * DDIM : 0); // W1a or W1b
    const float* __restrict__ Wc = W1 + 2 * DDIM * DDIM;          // W1c
    const float sgn = mat ? -1.0f : 1.0f;

    for (int d0 = 0; d0 < DDIM; d0 += 4) {
        float w[4];
#pragma unroll
        for (int dd = 0; dd < 4; ++dd)
            w[dd] = Wx[(d0 + dd) * DDIM + c] + sgn * Wc[(d0 + dd) * DDIM + c];
#pragma unroll
        for (int r = 0; r < 8; ++r) {
            float4 a4 = *(const float4*)&a_lds[(rg * 8 + r) * DDIM + d0];
            acc[r] += a4.x * w[0] + a4.y * w[1] + a4.z * w[2] + a4.w * w[3];
        }
    }

#pragma unroll
    for (int r = 0; r < 8; ++r)
        outp[(rblk * 16 + rg * 8 + r) * DDIM + c] = acc[r];
}

// ---------------------------------------------------------------------------
// Kernel 2: out[i][j] = (i>j) ? b2 + sum_c relu(U[i][c]+V[j][c])*W2[c] : 0
// grid = (32,32) tiles of 32x32, 256 threads, 2x2 micro-tile per thread.
// Upper-triangle tiles just zero-fill (d_out is poisoned by the harness).
// ---------------------------------------------------------------------------
__global__ __launch_bounds__(256) void pair_score(
    const float* __restrict__ U, const float* __restrict__ V,
    const float* __restrict__ W2, const float* __restrict__ b2,
    float* __restrict__ out)
{
    const int bj = blockIdx.x;   // column tile
    const int bi = blockIdx.y;   // row tile
    const int tid = threadIdx.x;

    if (bi < bj) {
        // strictly-upper tile: zero-fill, coalesced float4
        const int r  = tid >> 3;          // 0..31
        const int c4 = (tid & 7) << 2;    // 0,4,...,28
        *(float4*)&out[(bi * TS + r) * KDIM + bj * TS + c4] =
            make_float4(0.f, 0.f, 0.f, 0.f);
        return;
    }

    __shared__ float Ul[TS * LDP];
    __shared__ float Vl[TS * LDP];
    __shared__ float W2l[DDIM];

    {   // stage U/V tiles (32 rows x 128 floats = 1024 float4 each)
        const float4* us = (const float4*)(U + bi * TS * DDIM);
        const float4* vs = (const float4*)(V + bj * TS * DDIM);
#pragma unroll
        for (int k = 0; k < 4; ++k) {
            int idx = tid + k * 256;      // 0..1023
            int r   = idx >> 5;           // row (32 float4 per row)
            int c4  = idx & 31;           // float4 index within row
            *(float4*)&Ul[r * LDP + c4 * 4] = us[idx];
            *(float4*)&Vl[r * LDP + c4 * 4] = vs[idx];
        }
        if (tid < 32) *(float4*)&W2l[tid * 4] = *(const float4*)&W2[tid * 4];
    }
    __syncthreads();

    const int tj = tid & 15;
    const int ti = tid >> 4;
    const int i0 = ti * 2;
    const int j0 = tj * 2;
    const float b2v = b2[0];
    float a00 = b2v, a01 = b2v, a10 = b2v, a11 = b2v;

#pragma unroll
    for (int d = 0; d < DDIM; d += 4) {
        float4 u0 = *(const float4*)&Ul[i0 * LDP + d];
        float4 u1 = *(const float4*)&Ul[(i0 + 1) * LDP + d];
        float4 v0 = *(const float4*)&Vl[j0 * LDP + d];
        float4 v1 = *(const float4*)&Vl[(j0 + 1) * LDP + d];
        float4 w  = *(const float4*)&W2l[d];
#define STEP(C)                                   \
        a00 += fmaxf(u0.C + v0.C, 0.f) * w.C;     \
        a01 += fmaxf(u0.C + v1.C, 0.f) * w.C;     \
        a10 += fmaxf(u1.C + v0.C, 0.f) * w.C;     \
        a11 += fmaxf(u1.C + v1.C, 0.f) * w.C;
        STEP(x) STEP(y) STEP(z) STEP(w)
#undef STEP
    }

    const int gi0 = bi * TS + i0;
    const int gj0 = bj * TS + j0;
    float2 r0, r1;
    r0.x = (gi0     > gj0    ) ? a00 : 0.f;
    r0.y = (gi0     > gj0 + 1) ? a01 : 0.f;
    r1.x = (gi0 + 1 > gj0    ) ? a10 : 0.f;
    r1.y = (gi0 + 1 > gj0 + 1) ? a11 : 0.f;
    *(float2*)&out[ gi0      * KDIM + gj0] = r0;
    *(float2*)&out[(gi0 + 1) * KDIM + gj0] = r1;
}

// ---------------------------------------------------------------------------
extern "C" void kernel_launch(void* const* d_in, const int* in_sizes, int n_in,
                              void* d_out, int out_size, void* d_ws, size_t ws_size,
                              hipStream_t stream)
{
    const float* span = (const float*)d_in[0];
    const float* ant  = (const float*)d_in[1];
    const float* W1   = (const float*)d_in[2];
    const float* b1   = (const float*)d_in[3];
    const float* W2   = (const float*)d_in[4];
    const float* b2   = (const float*)d_in[5];
    float* out = (float*)d_out;

    float* U = (float*)d_ws;                 // 1024*128 floats
    float* V = U + KDIM * DDIM;              // 1024*128 floats (needs 1 MB ws)

    prep_uv<<<dim3(128), 256, 0, stream>>>(span, ant, W1, b1, U, V);
    pair_score<<<dim3(32, 32), 256, 0, stream>>>(U, V, W2, b2, out);
}

// Round 2
// 23.622 us; speedup vs baseline: 1.0250x; 1.0250x over previous
//
#include <hip/hip_runtime.h>

#define KDIM 1024
#define DDIM 128
#define LDP  132   // padded LDS row stride (floats); 528 B row, 16B-aligned

typedef float f2 __attribute__((ext_vector_type(2)));

// ---------------------------------------------------------------------------
// Kernel 1: U = span @ (W1a + W1c) + b1 ; V = ant @ (W1b - W1c)
// 256 blocks x 256 threads; 8 rows of one matrix per block.
// ---------------------------------------------------------------------------
__global__ __launch_bounds__(256) void prep_uv(
    const float* __restrict__ span, const float* __restrict__ ant,
    const float* __restrict__ W1,   const float* __restrict__ b1,
    float* __restrict__ U, float* __restrict__ V)
{
    __shared__ float a_lds[8 * DDIM];    // 4 KB

    const int mat  = blockIdx.x & 1;     // 0 -> U (span), 1 -> V (ant)
    const int rblk = blockIdx.x >> 1;    // 0..127, 8 rows each
    const float* __restrict__ A = mat ? ant : span;
    float* __restrict__ outp    = mat ? V : U;
    const int tid = threadIdx.x;

    // stage 8 input rows (1024 floats = 256 float4): one per thread
    {
        const float4* src = (const float4*)(A + rblk * 8 * DDIM);
        ((float4*)a_lds)[tid] = src[tid];
    }
    __syncthreads();

    const int c  = tid & 127;            // output column
    const int rg = tid >> 7;             // 0/1 -> rows rg*4 .. rg*4+3
    float acc[4];
    const float binit = mat ? 0.0f : b1[c];
#pragma unroll
    for (int r = 0; r < 4; ++r) acc[r] = binit;

    const float* __restrict__ Wx = W1 + (mat ? DDIM * DDIM : 0); // W1a or W1b
    const float* __restrict__ Wc = W1 + 2 * DDIM * DDIM;          // W1c
    const float sgn = mat ? -1.0f : 1.0f;

    for (int d0 = 0; d0 < DDIM; d0 += 4) {
        float w[4];
#pragma unroll
        for (int dd = 0; dd < 4; ++dd)
            w[dd] = Wx[(d0 + dd) * DDIM + c] + sgn * Wc[(d0 + dd) * DDIM + c];
#pragma unroll
        for (int r = 0; r < 4; ++r) {
            float4 a4 = *(const float4*)&a_lds[(rg * 4 + r) * DDIM + d0];
            acc[r] += a4.x * w[0] + a4.y * w[1] + a4.z * w[2] + a4.w * w[3];
        }
    }

#pragma unroll
    for (int r = 0; r < 4; ++r)
        outp[(rblk * 8 + rg * 4 + r) * DDIM + c] = acc[r];
}

// ---------------------------------------------------------------------------
// Kernel 2: out[i][j] = (i>j) ? b2 + sum_c relu(U[i][c]+V[j][c])*W2[c] : 0
// grid (32,32) of 32x32 tiles, 64 threads (1 wave) per block.
// Micro-tile 4x4 per thread with stride-8 lane mapping:
//   i = bi*32 + ti + 8a, j = bj*32 + tj + 8b  (ti=tid>>3, tj=tid&7)
// -> all LDS reads bank-conflict-free (addr mod 32 = ti*4 / tj*4).
// Packed f32 (float2 ext_vector) -> v_pk_{add,max,fma}_f32.
// ---------------------------------------------------------------------------
__global__ __launch_bounds__(64) void pair_score(
    const float* __restrict__ U, const float* __restrict__ V,
    const float* __restrict__ W2, const float* __restrict__ b2,
    float* __restrict__ out)
{
    const int bj  = blockIdx.x;   // column tile
    const int bi  = blockIdx.y;   // row tile
    const int tid = threadIdx.x;

    if (bi < bj) {
        // strictly-upper tile: zero-fill (harness poisons d_out)
        const float4 z4 = make_float4(0.f, 0.f, 0.f, 0.f);
#pragma unroll
        for (int k = 0; k < 8; ++k) {
            int idx = tid + k * 64;       // 0..511 (512 float4 in tile)
            int r   = idx >> 3;           // 8 float4 per 32-col row
            int c4  = idx & 7;
            *(float4*)&out[(bi * 32 + r) * KDIM + bj * 32 + c4 * 4] = z4;
        }
        return;
    }

    __shared__ float Ul[32 * LDP];
    __shared__ float Vl[32 * LDP];
    __shared__ float W2l[DDIM];

    {   // stage tiles: 1024 float4 each, 16 per thread
        const float4* us = (const float4*)(U + bi * 32 * DDIM);
        const float4* vs = (const float4*)(V + bj * 32 * DDIM);
#pragma unroll
        for (int k = 0; k < 16; ++k) {
            int idx = tid + k * 64;       // 0..1023
            int r   = idx >> 5;
            int c4  = idx & 31;
            *(float4*)&Ul[r * LDP + c4 * 4] = us[idx];
            *(float4*)&Vl[r * LDP + c4 * 4] = vs[idx];
        }
        if (tid < 32) *(float4*)&W2l[tid * 4] = *(const float4*)&W2[tid * 4];
    }
    __syncthreads();

    const int tj = tid & 7;
    const int ti = tid >> 3;
    const f2 z2 = {0.f, 0.f};

    f2 acc[4][4][2];
#pragma unroll
    for (int a = 0; a < 4; ++a)
#pragma unroll
        for (int b = 0; b < 4; ++b) {
            acc[a][b][0] = z2; acc[a][b][1] = z2;
        }

#pragma unroll 4
    for (int d = 0; d < DDIM; d += 4) {
        f2 ul[4][2], vl[4][2], w[2];
        {
            float4 x = *(const float4*)&W2l[d];
            w[0] = f2{x.x, x.y}; w[1] = f2{x.z, x.w};
        }
#pragma unroll
        for (int a = 0; a < 4; ++a) {
            float4 x = *(const float4*)&Ul[(ti + 8 * a) * LDP + d];
            ul[a][0] = f2{x.x, x.y}; ul[a][1] = f2{x.z, x.w};
        }
#pragma unroll
        for (int b = 0; b < 4; ++b) {
            float4 x = *(const float4*)&Vl[(tj + 8 * b) * LDP + d];
            vl[b][0] = f2{x.x, x.y}; vl[b][1] = f2{x.z, x.w};
        }
#pragma unroll
        for (int a = 0; a < 4; ++a)
#pragma unroll
            for (int b = 0; b < 4; ++b) {
                f2 t0 = __builtin_elementwise_max(ul[a][0] + vl[b][0], z2);
                f2 t1 = __builtin_elementwise_max(ul[a][1] + vl[b][1], z2);
                acc[a][b][0] += t0 * w[0];
                acc[a][b][1] += t1 * w[1];
            }
    }

    const float b2v = b2[0];
#pragma unroll
    for (int a = 0; a < 4; ++a) {
        const int gi = bi * 32 + ti + 8 * a;
#pragma unroll
        for (int b = 0; b < 4; ++b) {
            const int gj = bj * 32 + tj + 8 * b;
            f2 s2 = acc[a][b][0] + acc[a][b][1];
            float s = s2.x + s2.y + b2v;
            out[gi * KDIM + gj] = (gi > gj) ? s : 0.f;
        }
    }
}

// ---------------------------------------------------------------------------
extern "C" void kernel_launch(void* const* d_in, const int* in_sizes, int n_in,
                              void* d_out, int out_size, void* d_ws, size_t ws_size,
                              hipStream_t stream)
{
    const float* span = (const float*)d_in[0];
    const float* ant  = (const float*)d_in[1];
    const float* W1   = (const float*)d_in[2];
    const float* b1   = (const float*)d_in[3];
    const float* W2   = (const float*)d_in[4];
    const float* b2   = (const float*)d_in[5];
    float* out = (float*)d_out;

    float* U = (float*)d_ws;                 // 1024*128 floats
    float* V = U + KDIM * DDIM;              // 1024*128 floats (1 MB ws total)

    prep_uv<<<dim3(256), 256, 0, stream>>>(span, ant, W1, b1, U, V);
    pair_score<<<dim3(32, 32), 64, 0, stream>>>(U, V, W2, b2, out);
}